// Round 7
// baseline (139.815 us; speedup 1.0000x reference)
//
#include <hip/hip_runtime.h>
#include <math.h>
#include <stdint.h>

// Problem dims (fixed by setup_inputs)
#define B_N 256
#define C_N 1152
#define I_N 8
#define N_N 10
#define D_N 16

constexpr int C_PER    = 12;             // c's per block (ONE staging phase)
constexpr int C_CHUNKS = C_N / C_PER;    // 96
constexpr int B_TILE   = 32;             // 2 MFMA sub-tiles of 16 -> W reuse x2
constexpr int BLOCK    = 256;

typedef short v8s __attribute__((ext_vector_type(8)));   // 8 bf16 (4 VGPRs) MFMA A/B frag
typedef float v4f __attribute__((ext_vector_type(4)));   // 4 f32 MFMA C/D frag

// LDS pool (bytes):
//   Ws  (short): [12c][10n][16d][8i], c-stride 1288 (pad: quads de-banked) -> 30912 @ 0
//   xs  (short): [32b][100] (12c*8i + 4 pad)                               ->  6400 @ 30912
//   cfl (float): [12c][10n][33b-pad]                                       -> 15840 @ 37312
//   comb(float): [32b][164] ALIASES xs+cfl                                 -> 20992 @ 30912
constexpr int POOL_BYTES = 30912 + 6400 + 15840;  // 53152 -> 3 blocks/CU (grid is 3/CU)

__device__ __forceinline__ uint32_t bf16_rne(float f) {
    uint32_t u = __float_as_uint(f);
    return (u + 0x7FFFu + ((u >> 16) & 1u)) >> 16;
}
__device__ __forceinline__ uint32_t pack2(float a, float b) {
    return bf16_rne(a) | (bf16_rne(b) << 16);
}
__device__ __forceinline__ float bf2f(short s) {
    return __uint_as_float(((uint32_t)(uint16_t)s) << 16);
}

// One routing pass via MFMA, 32-batch blocks (2 sub-tiles T share one W staging).
// Sweep1 (per T): per (c,n) K-padded MFMA -> u[d,b]; logit = u.vs + 2 shfl; exp
//   streamed to cfl (owning quad), running Z, post-scale by rcp(Z).
// Sweep2 (per T): B-frag = bf16(coef*x); s[d,b] per n (waves own n-subsets)
//   accumulates in C-frags over all 12 c's; sacc[2T][3] kept in regs (24 VGPRs).
// FIRST: coef = 0.1 (softmax of zeros) -> sweep2 only, no vsum read.
template <bool FIRST>
__global__ __launch_bounds__(BLOCK, 3)
void route_pass(const float* __restrict__ x, const float* __restrict__ W,
                const float* __restrict__ vsum, float* __restrict__ p_s)
{
    __shared__ __align__(16) char pool[POOL_BYTES];
    short* Ws   = (short*)pool;
    short* xs   = (short*)(pool + 30912);
    float* cfl  = (float*)(pool + 37312);
    float* comb = (float*)(pool + 30912);

    const int tid   = threadIdx.x;
    const int wv    = tid >> 6;
    const int lane  = tid & 63;
    const int b     = lane & 15;    // D col = b; A-frag row m (=d) also lane&15
    const int quad  = lane >> 4;
    const int chunk = blockIdx.x;
    const int gb0   = blockIdx.y * B_TILE;
    const int c0    = chunk * C_PER;

    // ---- stage x: [32b][12c][8i] f32 -> bf16, coalesced float4 (3 it) ----
    {
        const float4* x4 = reinterpret_cast<const float4*>(x);
        #pragma unroll
        for (int it = 0; it < 3; ++it) {
            int e = (tid + BLOCK * it) * 4;        // < 3072
            int b2 = e / 96, r = e - b2 * 96;
            float4 v = x4[(size_t)(gb0 + b2) * 2304 + chunk * 24 + (r >> 2)];
            *reinterpret_cast<uint2*>(xs + b2 * 100 + r) =
                make_uint2(pack2(v.x, v.y), pack2(v.z, v.w));
        }
    }
    // ---- stage W: 12 c's f32 -> bf16 Ws[c][n][d][i], coalesced (15 it) ----
    {
        const float4* W4 = reinterpret_cast<const float4*>(W);
        #pragma unroll
        for (int it = 0; it < 15; ++it) {
            int e = (tid + BLOCK * it) * 4;        // < 15360
            int n = e / 1536, rr = e - n * 1536;
            int c = rr >> 7, k = rr & 127;
            float4 v = W4[(size_t)n * 36864 + (size_t)(c0 + c) * 32 + (k >> 2)];
            *reinterpret_cast<uint2*>(Ws + c * 1288 + n * 128 + k) =
                make_uint2(pack2(v.x, v.y), pack2(v.z, v.w));
        }
    }
    __syncthreads();

    const int ncnt = (wv < 2) ? 3 : 2;   // wave wv owns n = wv, wv+4, (wv+8)

    if (!FIRST) {
        // ---- sweep1: logits+softmax -> cfl, for both sub-tiles ----
        #pragma unroll
        for (int T = 0; T < 2; ++T) {
            v4f vs[N_N];
            #pragma unroll
            for (int n = 0; n < N_N; ++n) {
                const float4 t4 = *reinterpret_cast<const float4*>(
                    vsum + (((size_t)(gb0 + T * 16 + b) * N_N + n) * D_N + quad * 4));
                vs[n] = (v4f){t4.x, t4.y, t4.z, t4.w};
            }
            #pragma unroll
            for (int t = 0; t < 3; ++t) {
                const int cl = wv + 4 * t;
                const v8s xb = *reinterpret_cast<const v8s*>(
                    xs + (T * 16 + b) * 100 + cl * 8);   // k>=8 killed by A=0
                float Z = 0.f;
                #pragma unroll
                for (int n = 0; n < N_N; ++n) {
                    v8s wa = {0, 0, 0, 0, 0, 0, 0, 0};
                    if (quad == 0)   // only quad0 holds real k=0..7 (i)
                        wa = *reinterpret_cast<const v8s*>(Ws + cl * 1288 + n * 128 + b * 8);
                    v4f u = __builtin_amdgcn_mfma_f32_16x16x32_bf16(
                        wa, xb, (v4f){0.f, 0.f, 0.f, 0.f}, 0, 0, 0);
                    float l = u[0] * vs[n][0] + u[1] * vs[n][1]
                            + u[2] * vs[n][2] + u[3] * vs[n][3];
                    l += __shfl_xor(l, 16);
                    l += __shfl_xor(l, 32);
                    const float e1 = __expf(l);   // |l| <~ 3: no max-sub needed
                    Z += e1;
                    if ((n & 3) == quad)
                        cfl[cl * 330 + n * 33 + T * 16 + b] = e1;
                }
                const float rz = __builtin_amdgcn_rcpf(Z);
                #pragma unroll
                for (int jj = 0; jj < 3; ++jj) {
                    int n = 4 * jj + quad;
                    if (n < N_N) cfl[cl * 330 + n * 33 + T * 16 + b] *= rz;
                }
            }
        }
        __syncthreads();   // coef ready
    }

    // ---- sweep2: s accumulation, both sub-tiles, sacc in regs ----
    v4f sacc[2][3];
    #pragma unroll
    for (int T = 0; T < 2; ++T)
        #pragma unroll
        for (int jj = 0; jj < 3; ++jj) sacc[T][jj] = (v4f){0.f, 0.f, 0.f, 0.f};

    #pragma unroll
    for (int T = 0; T < 2; ++T) {
        #pragma unroll
        for (int Q = 0; Q < 3; ++Q) {
            const int clq = Q * 4 + quad;
            const v8s xq = *reinterpret_cast<const v8s*>(
                xs + (T * 16 + b) * 100 + clq * 8);
            float xf[8];
            #pragma unroll
            for (int j = 0; j < 8; ++j) xf[j] = bf2f(xq[j]);
            #pragma unroll
            for (int jj = 0; jj < 3; ++jj) {
                if (jj < ncnt) {
                    const int n = wv + 4 * jj;
                    const float cv = FIRST ? 0.1f
                        : cfl[clq * 330 + n * 33 + T * 16 + b];
                    union { v8s s; uint32_t u[4]; } zu;
                    zu.u[0] = pack2(cv * xf[0], cv * xf[1]);
                    zu.u[1] = pack2(cv * xf[2], cv * xf[3]);
                    zu.u[2] = pack2(cv * xf[4], cv * xf[5]);
                    zu.u[3] = pack2(cv * xf[6], cv * xf[7]);
                    const v8s wa = *reinterpret_cast<const v8s*>(
                        Ws + clq * 1288 + n * 128 + b * 8);
                    sacc[T][jj] = __builtin_amdgcn_mfma_f32_16x16x32_bf16(
                        wa, zu.s, sacc[T][jj], 0, 0, 0);
                }
            }
        }
    }

    __syncthreads();   // all xs/cfl reads done -> comb alias safe
    #pragma unroll
    for (int T = 0; T < 2; ++T)
        #pragma unroll
        for (int jj = 0; jj < 3; ++jj) {
            if (jj < ncnt) {
                const int n = wv + 4 * jj;
                #pragma unroll
                for (int r = 0; r < 4; ++r)
                    comb[(T * 16 + b) * 164 + n * 16 + quad * 4 + r] = sacc[T][jj][r];
            }
        }
    __syncthreads();
    // ---- drain comb -> p_s[chunk][b][n][d] (coalesced, 20 it) ----
    #pragma unroll
    for (int k = 0; k < 20; ++k) {
        int e = tid + BLOCK * k;          // < 5120 = bb*160 + n*16 + d
        int bb = e / 160, rem = e - bb * 160;
        p_s[((size_t)chunk * B_N + gb0 + bb) * 160 + rem] = comb[bb * 164 + rem];
    }
}

// Parallel reduce+squash: wave per group g = b*10+n; lane = h*4+q; h: 16 chunk-
// slices x6, q: float4 over d. phase0 vsum=v; phase1 vsum+=v; phase2 out=v.
__global__ __launch_bounds__(BLOCK)
void reduce_squash(const float* __restrict__ p_s, float* __restrict__ vsum,
                   float* __restrict__ out, int phase)
{
    const int warp = threadIdx.x >> 6;
    const int lane = threadIdx.x & 63;
    const int g    = blockIdx.x * 4 + warp;   // 0..2559 == b*10+n
    const int q    = lane & 3;
    const int h    = lane >> 2;

    float4 s = make_float4(0.f, 0.f, 0.f, 0.f);
    #pragma unroll
    for (int m = 0; m < C_CHUNKS / 16; ++m) {   // 6
        const int cc = h + 16 * m;
        float4 v = *reinterpret_cast<const float4*>(
            &p_s[((size_t)cc * (B_N * N_N) + g) * D_N + q * 4]);
        s.x += v.x; s.y += v.y; s.z += v.z; s.w += v.w;
    }
    #pragma unroll
    for (int off = 4; off < 64; off <<= 1) {
        s.x += __shfl_xor(s.x, off);
        s.y += __shfl_xor(s.y, off);
        s.z += __shfl_xor(s.z, off);
        s.w += __shfl_xor(s.w, off);
    }
    float sq = s.x * s.x + s.y * s.y + s.z * s.z + s.w * s.w;
    sq += __shfl_xor(sq, 1);
    sq += __shfl_xor(sq, 2);

    const float scale = (sq / (1.f + sq)) / (sqrtf(sq) + 1e-8f);
    const float4 v = make_float4(scale * s.x, scale * s.y, scale * s.z, scale * s.w);

    if (h == 0) {
        if (phase == 0) {
            *reinterpret_cast<float4*>(&vsum[(size_t)g * D_N + q * 4]) = v;
        } else if (phase == 1) {
            float4 o = *reinterpret_cast<const float4*>(&vsum[(size_t)g * D_N + q * 4]);
            *reinterpret_cast<float4*>(&vsum[(size_t)g * D_N + q * 4]) =
                make_float4(o.x + v.x, o.y + v.y, o.z + v.z, o.w + v.w);
        } else {
            *reinterpret_cast<float4*>(&out[(size_t)g * D_N + q * 4]) = v;
        }
    }
}

extern "C" void kernel_launch(void* const* d_in, const int* in_sizes, int n_in,
                              void* d_out, int out_size, void* d_ws, size_t ws_size,
                              hipStream_t stream)
{
    const float* x = (const float*)d_in[0];
    const float* W = (const float*)d_in[1];
    float* out  = (float*)d_out;
    float* vsum = (float*)d_ws;                         // B*N*D floats
    float* p_s  = vsum + (size_t)B_N * N_N * D_N;       // C_CHUNKS*B*N*D floats (~15.7 MB)

    dim3 grid(C_CHUNKS, B_N / B_TILE);                  // 96 x 8 = 768 = 3 blocks/CU
    dim3 blk(BLOCK);
    dim3 rgrid((B_N * N_N) / 4);

    // pass 0: coef = 1/N (softmax of zero logits) -> v0
    route_pass<true><<<grid, blk, 0, stream>>>(x, W, nullptr, p_s);
    reduce_squash<<<rgrid, blk, 0, stream>>>(p_s, vsum, out, 0);
    // pass 1: logits = dot(u_hat, v0) -> v1, vsum = v0+v1
    route_pass<false><<<grid, blk, 0, stream>>>(x, W, vsum, p_s);
    reduce_squash<<<rgrid, blk, 0, stream>>>(p_s, vsum, out, 1);
    // pass 2: logits = dot(u_hat, v0+v1) -> output v2
    route_pass<false><<<grid, blk, 0, stream>>>(x, W, vsum, p_s);
    reduce_squash<<<rgrid, blk, 0, stream>>>(p_s, vsum, out, 2);
}

// Round 8
// 132.623 us; speedup vs baseline: 1.0542x; 1.0542x over previous
//
#include <hip/hip_runtime.h>
#include <math.h>
#include <stdint.h>

// Problem dims (fixed by setup_inputs)
#define B_N 256
#define C_N 1152
#define I_N 8
#define N_N 10
#define D_N 16

constexpr int C_PER    = 12;             // c's per block
constexpr int STAGE_C  = 4;              // c's per W staging round (1 per wave in sweep1)
constexpr int N_STAGES = 3;
constexpr int C_CHUNKS = C_N / C_PER;    // 96
constexpr int B_TILE   = 16;
constexpr int BLOCK    = 256;
// grid = 96 x 16 = 1536 blocks = 6 blocks/CU  <- the point of this round

typedef short v8s __attribute__((ext_vector_type(8)));   // 8 bf16 (4 VGPRs) MFMA A/B frag
typedef float v4f __attribute__((ext_vector_type(4)));   // 4 f32 MFMA C/D frag

// LDS pool (bytes) -- total 26672 B -> 6 blocks/CU (163840/26880granule = 6):
//   Ws  (short): [4c][10n][16d][8i], c-stride 1280       -> 10240 @ 0
//   xs  (short): [16b][104] (12c*8i + 8 pad, 16B-aligned) ->  3328 @ 10240
//   cfl (float): [4c][163] (10n*16b + 3 pad)             ->  2608 @ 13568
//   vss (float): [16b][164] (10n*16d + 4 pad)            -> 10496 @ 16176
//   comb(float): [16b][164] ALIASES Ws/xs                -> 10496 @ 0
constexpr int POOL_BYTES = 16176 + 10496;

__device__ __forceinline__ uint32_t bf16_rne(float f) {
    uint32_t u = __float_as_uint(f);
    return (u + 0x7FFFu + ((u >> 16) & 1u)) >> 16;
}
__device__ __forceinline__ uint32_t pack2(float a, float b) {
    return bf16_rne(a) | (bf16_rne(b) << 16);
}
__device__ __forceinline__ float bf2f(short s) {
    return __uint_as_float(((uint32_t)(uint16_t)s) << 16);
}

// One routing pass via MFMA. D[row=(lane>>4)*4+reg -> d][col=lane&15 -> b].
// Sweep1: per (c,n) K-padded MFMA -> u[d,b]; logit = u . vss + 2 shfl; exp
//   streamed to cfl; running Z; post-scale by rcp(Z). vsum lives in LDS (vss),
//   not registers -> ~40 fewer VGPRs, fits __launch_bounds__(256,6).
// Sweep2: B-frag = bf16(coef*x); s[d,b] per n (waves own n-subsets) in C-frags.
// FIRST: coef = 0.1 (softmax of zeros) -> sweep2 only, no vsum read.
template <bool FIRST>
__global__ __launch_bounds__(BLOCK, 6)
void route_pass(const float* __restrict__ x, const float* __restrict__ W,
                const float* __restrict__ vsum, float* __restrict__ p_s)
{
    __shared__ __align__(16) char pool[POOL_BYTES];
    short* Ws   = (short*)pool;
    short* xs   = (short*)(pool + 10240);
    float* cfl  = (float*)(pool + 13568);
    float* vss  = (float*)(pool + 16176);
    float* comb = (float*)(pool + 0);

    const int tid   = threadIdx.x;
    const int wv    = tid >> 6;
    const int lane  = tid & 63;
    const int b     = lane & 15;    // D col = b; A-frag row m (=d) also lane&15
    const int quad  = lane >> 4;
    const int chunk = blockIdx.x;
    const int gb0   = blockIdx.y * B_TILE;
    const int c0    = chunk * C_PER;

    // ---- stage x: [16b][12c][8i] f32 -> bf16, coalesced float4 ----
    {
        const float4* x4 = reinterpret_cast<const float4*>(x);
        #pragma unroll
        for (int it = 0; it < 2; ++it) {
            int e = (tid + BLOCK * it) * 4;
            if (e < 1536) {
                int b2 = e / 96, r = e - b2 * 96;
                float4 v = x4[(size_t)(gb0 + b2) * 2304 + chunk * 24 + (r >> 2)];
                *reinterpret_cast<uint2*>(xs + b2 * 104 + r) =
                    make_uint2(pack2(v.x, v.y), pack2(v.z, v.w));
            }
        }
    }
    // ---- stage vsum tile: [16b][10n*16d] f32 -> vss (float4) ----
    if (!FIRST) {
        #pragma unroll
        for (int it = 0; it < 3; ++it) {
            int e = (tid + BLOCK * it) * 4;
            if (e < 2560) {
                int b2 = e / 160, r = e - b2 * 160;
                float4 v = *reinterpret_cast<const float4*>(
                    vsum + (size_t)(gb0 + b2) * 160 + r);
                *reinterpret_cast<float4*>(vss + b2 * 164 + r) = v;
            }
        }
    }

    const int ncnt = (wv < 2) ? 3 : 2;   // wave wv owns n = wv, wv+4, (wv+8)
    v4f sacc[3];
    sacc[0] = (v4f){0.f, 0.f, 0.f, 0.f};
    sacc[1] = (v4f){0.f, 0.f, 0.f, 0.f};
    sacc[2] = (v4f){0.f, 0.f, 0.f, 0.f};

    const float4* W4 = reinterpret_cast<const float4*>(W);

    for (int st = 0; st < N_STAGES; ++st) {
        __syncthreads();   // prior sweep2 Ws/cfl reads done; x/vss staged (st=0)
        // ---- stage W: 4 c's f32 -> bf16 Ws[c][n][d][i], coalesced (5 it) ----
        #pragma unroll
        for (int it = 0; it < 5; ++it) {
            int e = (tid + BLOCK * it) * 4;   // < 5120
            int n = e >> 9, rr = e & 511;
            int c = rr >> 7, k = rr & 127;
            float4 v = W4[(size_t)n * 36864 + (size_t)(c0 + st * STAGE_C + c) * 32 + (k >> 2)];
            *reinterpret_cast<uint2*>(Ws + c * 1280 + n * 128 + k) =
                make_uint2(pack2(v.x, v.y), pack2(v.z, v.w));
        }
        __syncthreads();

        if (!FIRST) {
            // ---- sweep1: one c per wave (cl = wv), balanced ----
            const int cl = wv;
            const v8s xb = *reinterpret_cast<const v8s*>(
                xs + b * 104 + (st * STAGE_C + cl) * 8);   // k>=8 killed by A=0
            float Z = 0.f;
            #pragma unroll
            for (int n = 0; n < N_N; ++n) {
                v8s wa = {0, 0, 0, 0, 0, 0, 0, 0};
                if (quad == 0)   // only quad0 holds real k=0..7 (i)
                    wa = *reinterpret_cast<const v8s*>(Ws + cl * 1280 + n * 128 + b * 8);
                v4f u = __builtin_amdgcn_mfma_f32_16x16x32_bf16(
                    wa, xb, (v4f){0.f, 0.f, 0.f, 0.f}, 0, 0, 0);
                const float4 vs4 = *reinterpret_cast<const float4*>(
                    vss + b * 164 + n * 16 + quad * 4);
                float l = u[0] * vs4.x + u[1] * vs4.y + u[2] * vs4.z + u[3] * vs4.w;
                l += __shfl_xor(l, 16);
                l += __shfl_xor(l, 32);
                const float e1 = __expf(l);   // |l| <~ 3: no max-sub needed
                Z += e1;
                if ((n & 3) == quad)
                    cfl[cl * 163 + n * 16 + b] = e1;
            }
            const float rz = __builtin_amdgcn_rcpf(Z);
            #pragma unroll
            for (int jj = 0; jj < 3; ++jj) {
                int n = 4 * jj + quad;
                if (n < N_N) cfl[cl * 163 + n * 16 + b] *= rz;
            }
            __syncthreads();   // coef ready
        }

        // ---- sweep2: lane's c = quad; waves own n-subsets ----
        {
            const int cfull = st * STAGE_C + quad;
            const v8s xq = *reinterpret_cast<const v8s*>(xs + b * 104 + cfull * 8);
            float xf[8];
            #pragma unroll
            for (int j = 0; j < 8; ++j) xf[j] = bf2f(xq[j]);
            #pragma unroll
            for (int jj = 0; jj < 3; ++jj) {
                if (jj < ncnt) {
                    const int n = wv + 4 * jj;
                    const float cv = FIRST ? 0.1f : cfl[quad * 163 + n * 16 + b];
                    union { v8s s; uint32_t u[4]; } zu;
                    zu.u[0] = pack2(cv * xf[0], cv * xf[1]);
                    zu.u[1] = pack2(cv * xf[2], cv * xf[3]);
                    zu.u[2] = pack2(cv * xf[4], cv * xf[5]);
                    zu.u[3] = pack2(cv * xf[6], cv * xf[7]);
                    const v8s wa = *reinterpret_cast<const v8s*>(
                        Ws + quad * 1280 + n * 128 + b * 8);
                    sacc[jj] = __builtin_amdgcn_mfma_f32_16x16x32_bf16(
                        wa, zu.s, sacc[jj], 0, 0, 0);
                }
            }
        }
    }

    __syncthreads();   // all Ws/xs reads done -> comb alias safe
    #pragma unroll
    for (int jj = 0; jj < 3; ++jj) {
        if (jj < ncnt) {
            const int n = wv + 4 * jj;
            #pragma unroll
            for (int r = 0; r < 4; ++r)
                comb[b * 164 + n * 16 + quad * 4 + r] = sacc[jj][r];
        }
    }
    __syncthreads();
    // ---- drain comb -> p_s[chunk][b][n][d] (coalesced float4, 3 it) ----
    #pragma unroll
    for (int it = 0; it < 3; ++it) {
        int f = tid + BLOCK * it;
        if (f < 640) {
            int e = f * 4;
            int bb = e / 160, rem = e - bb * 160;
            float4 v = *reinterpret_cast<const float4*>(comb + bb * 164 + rem);
            *reinterpret_cast<float4*>(
                &p_s[((size_t)chunk * B_N + gb0 + bb) * 160 + rem]) = v;
        }
    }
}

// Parallel reduce+squash: wave per group g = b*10+n; lane = h*4+q; h: 16 chunk-
// slices x6, q: float4 over d. phase0 vsum=v; phase1 vsum+=v; phase2 out=v.
__global__ __launch_bounds__(BLOCK)
void reduce_squash(const float* __restrict__ p_s, float* __restrict__ vsum,
                   float* __restrict__ out, int phase)
{
    const int warp = threadIdx.x >> 6;
    const int lane = threadIdx.x & 63;
    const int g    = blockIdx.x * 4 + warp;   // 0..2559 == b*10+n
    const int q    = lane & 3;
    const int h    = lane >> 2;

    float4 s = make_float4(0.f, 0.f, 0.f, 0.f);
    #pragma unroll
    for (int m = 0; m < C_CHUNKS / 16; ++m) {   // 6
        const int cc = h + 16 * m;
        float4 v = *reinterpret_cast<const float4*>(
            &p_s[((size_t)cc * (B_N * N_N) + g) * D_N + q * 4]);
        s.x += v.x; s.y += v.y; s.z += v.z; s.w += v.w;
    }
    #pragma unroll
    for (int off = 4; off < 64; off <<= 1) {
        s.x += __shfl_xor(s.x, off);
        s.y += __shfl_xor(s.y, off);
        s.z += __shfl_xor(s.z, off);
        s.w += __shfl_xor(s.w, off);
    }
    float sq = s.x * s.x + s.y * s.y + s.z * s.z + s.w * s.w;
    sq += __shfl_xor(sq, 1);
    sq += __shfl_xor(sq, 2);

    const float scale = (sq / (1.f + sq)) / (sqrtf(sq) + 1e-8f);
    const float4 v = make_float4(scale * s.x, scale * s.y, scale * s.z, scale * s.w);

    if (h == 0) {
        if (phase == 0) {
            *reinterpret_cast<float4*>(&vsum[(size_t)g * D_N + q * 4]) = v;
        } else if (phase == 1) {
            float4 o = *reinterpret_cast<const float4*>(&vsum[(size_t)g * D_N + q * 4]);
            *reinterpret_cast<float4*>(&vsum[(size_t)g * D_N + q * 4]) =
                make_float4(o.x + v.x, o.y + v.y, o.z + v.z, o.w + v.w);
        } else {
            *reinterpret_cast<float4*>(&out[(size_t)g * D_N + q * 4]) = v;
        }
    }
}

extern "C" void kernel_launch(void* const* d_in, const int* in_sizes, int n_in,
                              void* d_out, int out_size, void* d_ws, size_t ws_size,
                              hipStream_t stream)
{
    const float* x = (const float*)d_in[0];
    const float* W = (const float*)d_in[1];
    float* out  = (float*)d_out;
    float* vsum = (float*)d_ws;                         // B*N*D floats
    float* p_s  = vsum + (size_t)B_N * N_N * D_N;       // C_CHUNKS*B*N*D floats (~15.7 MB)

    dim3 grid(C_CHUNKS, B_N / B_TILE);                  // 96 x 16 = 1536 = 6 blocks/CU
    dim3 blk(BLOCK);
    dim3 rgrid((B_N * N_N) / 4);

    // pass 0: coef = 1/N (softmax of zero logits) -> v0
    route_pass<true><<<grid, blk, 0, stream>>>(x, W, nullptr, p_s);
    reduce_squash<<<rgrid, blk, 0, stream>>>(p_s, vsum, out, 0);
    // pass 1: logits = dot(u_hat, v0) -> v1, vsum = v0+v1
    route_pass<false><<<grid, blk, 0, stream>>>(x, W, vsum, p_s);
    reduce_squash<<<rgrid, blk, 0, stream>>>(p_s, vsum, out, 1);
    // pass 2: logits = dot(u_hat, v0+v1) -> output v2
    route_pass<false><<<grid, blk, 0, stream>>>(x, W, vsum, p_s);
    reduce_squash<<<rgrid, blk, 0, stream>>>(p_s, vsum, out, 2);
}